// Round 1
// baseline (486.731 us; speedup 1.0000x reference)
//
#include <hip/hip_runtime.h>
#include <hip/hip_bf16.h>

#define NN 50000
#define NE 800000
#define FD 256
#define LD 128
#define BN_EPS 1e-5f

typedef __bf16 bf16_t;
typedef bf16_t bf16x8 __attribute__((ext_vector_type(8)));
typedef float f32x4 __attribute__((ext_vector_type(4)));

// ---------------- CSR build ----------------

__global__ __launch_bounds__(256) void k_count(const int* __restrict__ dst,
                                               int* __restrict__ cnt) {
  int i = blockIdx.x * blockDim.x + threadIdx.x;
  if (i < NE) atomicAdd(&cnt[dst[i]], 1);
}

__global__ __launch_bounds__(256) void k_scanA(const int* __restrict__ cnt,
                                               int* __restrict__ row_ptr,
                                               int* __restrict__ partials) {
  __shared__ int ws[4];
  int b = blockIdx.x, t = threadIdx.x;
  int base = b * 1024 + t * 4;
  int vals[4];
#pragma unroll
  for (int j = 0; j < 4; ++j) vals[j] = (base + j < NN) ? cnt[base + j] : 0;
  int tsum = vals[0] + vals[1] + vals[2] + vals[3];
  int lane = t & 63, wid = t >> 6;
  int x = tsum;
#pragma unroll
  for (int off = 1; off < 64; off <<= 1) {
    int y = __shfl_up(x, off, 64);
    if (lane >= off) x += y;
  }
  if (lane == 63) ws[wid] = x;
  __syncthreads();
  int woff = 0;
  for (int w = 0; w < wid; ++w) woff += ws[w];
  int run = woff + x - tsum;
#pragma unroll
  for (int j = 0; j < 4; ++j) {
    if (base + j < NN) row_ptr[base + j] = run;
    run += vals[j];
  }
  if (t == 255) partials[b] = woff + x;
}

__global__ void k_scanB(int* __restrict__ partials, int* __restrict__ row_ptr,
                        int nblk) {
  int lane = threadIdx.x;
  int v = (lane < nblk) ? partials[lane] : 0;
  int x = v;
#pragma unroll
  for (int off = 1; off < 64; off <<= 1) {
    int y = __shfl_up(x, off, 64);
    if (lane >= off) x += y;
  }
  if (lane < nblk) partials[lane] = x - v;
  if (lane == 0) row_ptr[NN] = NE;
}

// scanC + dinv fused
__global__ __launch_bounds__(256) void k_scanC(int* __restrict__ row_ptr,
                                               const int* __restrict__ partials,
                                               const int* __restrict__ cnt,
                                               float* __restrict__ dinv) {
  int b = blockIdx.x;
  int off = partials[b];
  int base = b * 1024 + threadIdx.x * 4;
#pragma unroll
  for (int j = 0; j < 4; ++j)
    if (base + j < NN) {
      row_ptr[base + j] += off;
      dinv[base + j] = rsqrtf(1.0f + (float)cnt[base + j]);
    }
}

__global__ __launch_bounds__(256) void k_fill(const int* __restrict__ src,
                                              const int* __restrict__ dst,
                                              const int* __restrict__ row_ptr,
                                              int* __restrict__ cursor,
                                              int* __restrict__ col) {
  int i = blockIdx.x * blockDim.x + threadIdx.x;
  if (i < NE) {
    int d = dst[i];
    int p = atomicAdd(&cursor[d], 1);
    col[row_ptr[d] + p] = src[i];
  }
}

// ---------------- weight convert to MFMA-fragment-swizzled bf16 ------------
__global__ __launch_bounds__(256) void k_convw(
    const float* __restrict__ W0, const float* __restrict__ W1,
    const float* __restrict__ Wmu, const float* __restrict__ bmu,
    const float* __restrict__ Wlv, const float* __restrict__ blv,
    bf16_t* __restrict__ W0s, bf16_t* __restrict__ W1s,
    bf16_t* __restrict__ Whs, float* __restrict__ biash) {
  int k = blockIdx.x, n = threadIdx.x;
  int chunk = (n >> 4) * 8 + (k >> 5);
  int slot = ((k >> 3) & 3) * 16 + (n & 15);
  int idx = chunk * 512 + slot * 8 + (k & 7);
  W0s[idx] = (bf16_t)W0[k * 256 + n];
  W1s[idx] = (bf16_t)W1[k * 256 + n];
  float wh = (n < 128) ? Wmu[k * 128 + n] : Wlv[k * 128 + (n - 128)];
  Whs[idx] = (bf16_t)wh;
  if (k == 0) biash[n] = (n < 128) ? bmu[n] : blv[n - 128];
}

// ---------------- barrier-free MFMA GEMM, batched raw loads ----------------
// bf16 activations (a_f32==0) are in SLICE-MAJOR layout [8][NN][32]:
// feature f of node r lives at (f>>5)*NN*32 + r*32 + (f&31).
// Note slice == kb for the A-fragment k-blocks, so only addressing changes.
// Cb output is written slice-major too.
__global__ __launch_bounds__(256) void k_mgemm(
    const void* __restrict__ Ap, int a_f32, const bf16_t* __restrict__ Wswz,
    bf16_t* __restrict__ Cb, float* __restrict__ Cf, int M,
    const float* __restrict__ bn_scale, const float* __restrict__ bn_shift,
    const float* __restrict__ row_scale, const float* __restrict__ col_bias,
    int split) {
  __shared__ bf16_t Ws[64 * 512];  // 64 chunks x 1 KB
  const int tid = threadIdx.x;
  const int half = blockIdx.y;
  {
    const bf16_t* srcW = Wswz + (size_t)half * 64 * 512;
    bf16x8 wraw[16];
#pragma unroll
    for (int i = 0; i < 16; ++i)
      wraw[i] = *(const bf16x8*)&srcW[(i * 256 + tid) * 8];
#pragma unroll
    for (int i = 0; i < 16; ++i) *(bf16x8*)&Ws[(i * 256 + tid) * 8] = wraw[i];
  }
  __syncthreads();

  const int wave = tid >> 6, lane = tid & 63;
  const int m = lane & 15, q = lane >> 4;  // A-frag: row m, k-octet q
  const int row0 = blockIdx.x * 128 + wave * 32;
  const int rg0 = row0 + m, rg1 = row0 + 16 + m;
  const int rc0 = rg0 < M ? rg0 : M - 1;
  const int rc1 = rg1 < M ? rg1 : M - 1;

  bf16x8 af[2][8];
  if (a_f32) {
    const float* p0 = (const float*)Ap + (size_t)rc0 * 256 + q * 8;
    const float* p1 = (const float*)Ap + (size_t)rc1 * 256 + q * 8;
#pragma unroll
    for (int g = 0; g < 2; ++g) {
      const float* p = g ? p1 : p0;
      float4 f0[8], f1[8];
#pragma unroll
      for (int kb = 0; kb < 8; ++kb) {
        f0[kb] = *(const float4*)(p + kb * 32);
        f1[kb] = *(const float4*)(p + kb * 32 + 4);
      }
#pragma unroll
      for (int kb = 0; kb < 8; ++kb) {
        bf16x8 fr;
        fr[0] = (bf16_t)f0[kb].x; fr[1] = (bf16_t)f0[kb].y;
        fr[2] = (bf16_t)f0[kb].z; fr[3] = (bf16_t)f0[kb].w;
        fr[4] = (bf16_t)f1[kb].x; fr[5] = (bf16_t)f1[kb].y;
        fr[6] = (bf16_t)f1[kb].z; fr[7] = (bf16_t)f1[kb].w;
        af[g][kb] = fr;
      }
    }
  } else {
    const bf16_t* pA = (const bf16_t*)Ap;
    bf16x8 raw[16];
#pragma unroll
    for (int kb = 0; kb < 8; ++kb) {
      // slice-major: slice == kb, contiguous 64 B per node
      raw[kb * 2 + 0] =
          *(const bf16x8*)&pA[((size_t)kb * NN + rc0) * 32 + q * 8];
      raw[kb * 2 + 1] =
          *(const bf16x8*)&pA[((size_t)kb * NN + rc1) * 32 + q * 8];
    }
#pragma unroll
    for (int kb = 0; kb < 8; ++kb) {
      float s[8], h[8];
      if (bn_scale) {
        float4 s0 = *(const float4*)&bn_scale[kb * 32 + q * 8];
        float4 s1 = *(const float4*)&bn_scale[kb * 32 + q * 8 + 4];
        float4 h0 = *(const float4*)&bn_shift[kb * 32 + q * 8];
        float4 h1 = *(const float4*)&bn_shift[kb * 32 + q * 8 + 4];
        s[0] = s0.x; s[1] = s0.y; s[2] = s0.z; s[3] = s0.w;
        s[4] = s1.x; s[5] = s1.y; s[6] = s1.z; s[7] = s1.w;
        h[0] = h0.x; h[1] = h0.y; h[2] = h0.z; h[3] = h0.w;
        h[4] = h1.x; h[5] = h1.y; h[6] = h1.z; h[7] = h1.w;
      }
#pragma unroll
      for (int g = 0; g < 2; ++g) {
        bf16x8 r = raw[kb * 2 + g];
        bf16x8 fr;
#pragma unroll
        for (int j = 0; j < 8; ++j) {
          float v = (float)r[j];
          if (bn_scale) v = fmaxf(fmaf(v, s[j], h[j]), 0.f);
          fr[j] = (bf16_t)v;
        }
        af[g][kb] = fr;
      }
    }
  }

  f32x4 acc[2][8] = {};
#pragma unroll
  for (int nt = 0; nt < 8; ++nt) {
#pragma unroll
    for (int kb = 0; kb < 8; ++kb) {
      bf16x8 b = *(const bf16x8*)&Ws[(nt * 8 + kb) * 512 + lane * 8];
      acc[0][nt] = __builtin_amdgcn_mfma_f32_16x16x32_bf16(af[0][kb], b,
                                                           acc[0][nt], 0, 0, 0);
      acc[1][nt] = __builtin_amdgcn_mfma_f32_16x16x32_bf16(af[1][kb], b,
                                                           acc[1][nt], 0, 0, 0);
    }
  }

  // epilogue: D row_local = q*4 + r, col_local = m  [m89-verified layout]
#pragma unroll
  for (int g = 0; g < 2; ++g) {
#pragma unroll
    for (int r = 0; r < 4; ++r) {
      int row = row0 + g * 16 + q * 4 + r;
      if (row >= M) continue;
      float rs = row_scale ? row_scale[row] : 1.0f;
#pragma unroll
      for (int nt = 0; nt < 8; ++nt) {
        int col = half * 128 + nt * 16 + m;
        float v = acc[g][nt][r] * rs;
        if (col_bias) v += col_bias[col];
        if (Cb) {
          // slice-major write
          Cb[((size_t)(col >> 5) * NN + row) * 32 + (col & 31)] = (bf16_t)v;
        } else if (!split) {
          Cf[(size_t)row * 256 + col] = v;
        } else {
          if (col < 128)
            Cf[(size_t)row * 128 + col] = v;
          else
            Cf[(size_t)(M + row) * 128 + (col - 128)] = v;
        }
      }
    }
  }
}

// ---------------- SpMM + fused BN stats, XCD-pinned feature slices --------
// g / out are slice-major [8][NN][32]. Block handles slice s = blockIdx.x & 7
// (round-robin dispatch pins slice s to XCD s, so the 3.2 MB slice stays in
// that XCD's 4 MB L2). Teams of 4 lanes, 1 dst row per team, 64 rows/block.
// Streams (col, output) use non-temporal accesses to avoid evicting the slice.
__global__ __launch_bounds__(256) void k_spmm(const bf16_t* __restrict__ g,
                                              const int* __restrict__ row_ptr,
                                              const int* __restrict__ col,
                                              const float* __restrict__ dinv,
                                              bf16_t* __restrict__ out,
                                              float* __restrict__ stats) {
  __shared__ float sbuf[64][32];
  const int s = blockIdx.x & 7;
  const int grp = blockIdx.x >> 3;
  const int team = threadIdx.x >> 2, tl = threadIdx.x & 3;
  const int dst = grp * 64 + team;
  const bf16_t* gs = g + (size_t)s * NN * 32;
  const size_t fo = (size_t)tl * 8;
  float s1[8] = {}, s2[8] = {};
  if (dst < NN) {
    int sidx = row_ptr[dst], e = row_ptr[dst + 1];
    float a[8];
    {
      bf16x8 sv = *(const bf16x8*)&gs[(size_t)dst * 32 + fo];
#pragma unroll
      for (int j = 0; j < 8; ++j) a[j] = (float)sv[j];
    }
    for (int b0 = sidx; b0 < e; b0 += 8) {
      int rem = e - b0;
      if (rem >= 8) {
        int cv0 = __builtin_nontemporal_load(&col[b0 + tl]);
        int cv1 = __builtin_nontemporal_load(&col[b0 + 4 + tl]);
        bf16x8 v[8];
#pragma unroll
        for (int u = 0; u < 8; ++u) {
          int sn = __shfl(u < 4 ? cv0 : cv1, u & 3, 4);
          v[u] = *(const bf16x8*)&gs[(size_t)sn * 32 + fo];
        }
#pragma unroll
        for (int u = 0; u < 8; ++u)
#pragma unroll
          for (int j = 0; j < 8; ++j) a[j] += (float)v[u][j];
      } else {
        int cv0 = (b0 + tl < e) ? col[b0 + tl] : 0;
        int cv1 = (b0 + 4 + tl < e) ? col[b0 + 4 + tl] : 0;
#pragma unroll
        for (int u = 0; u < 8; ++u) {
          if (u < rem) {
            int sn = __shfl(u < 4 ? cv0 : cv1, u & 3, 4);
            bf16x8 v = *(const bf16x8*)&gs[(size_t)sn * 32 + fo];
#pragma unroll
            for (int j = 0; j < 8; ++j) a[j] += (float)v[j];
          }
        }
      }
    }
    float dv = dinv[dst];
    bf16x8 ov;
#pragma unroll
    for (int j = 0; j < 8; ++j) ov[j] = (bf16_t)(a[j] * dv);
    __builtin_nontemporal_store(
        ov, (bf16x8*)&out[(size_t)s * NN * 32 + (size_t)dst * 32 + fo]);
#pragma unroll
    for (int j = 0; j < 8; ++j) {
      float vq = (float)ov[j];
      s1[j] += vq;
      s2[j] = fmaf(vq, vq, s2[j]);
    }
  }
  // block reduction of stats (32 feats of this slice across 64 teams)
#pragma unroll
  for (int j = 0; j < 8; ++j) sbuf[team][tl * 8 + j] = s1[j];
  __syncthreads();
  if (threadIdx.x < 32) {
    float tot = 0.f;
#pragma unroll
    for (int w = 0; w < 64; ++w) tot += sbuf[w][threadIdx.x];
    atomicAdd(&stats[s * 32 + threadIdx.x], tot);
  }
  __syncthreads();
#pragma unroll
  for (int j = 0; j < 8; ++j) sbuf[team][tl * 8 + j] = s2[j];
  __syncthreads();
  if (threadIdx.x < 32) {
    float tot = 0.f;
#pragma unroll
    for (int w = 0; w < 64; ++w) tot += sbuf[w][threadIdx.x];
    atomicAdd(&stats[256 + s * 32 + threadIdx.x], tot);
  }
}

__global__ __launch_bounds__(256) void k_bnfinal(const float* __restrict__ stats,
                                                 const float* __restrict__ gamma,
                                                 const float* __restrict__ beta,
                                                 float* __restrict__ bnsc,
                                                 float* __restrict__ bnsh) {
  int t = threadIdx.x;
  float mean = stats[t] * (1.0f / NN);
  float var = stats[256 + t] * (1.0f / NN) - mean * mean;
  float rs = rsqrtf(var + BN_EPS);
  float sc = gamma[t] * rs;
  bnsc[t] = sc;
  bnsh[t] = beta[t] - mean * sc;
}

// ---------------- launch ----------------
extern "C" void kernel_launch(void* const* d_in, const int* in_sizes, int n_in,
                              void* d_out, int out_size, void* d_ws, size_t ws_size,
                              hipStream_t stream) {
  const float* x = (const float*)d_in[0];
  const int* ei = (const int*)d_in[1];
  const int* esrc = ei;
  const int* edst = ei + NE;
  const float* W0 = (const float*)d_in[2];
  const float* gamma0 = (const float*)d_in[4];
  const float* beta0 = (const float*)d_in[5];
  const float* W1 = (const float*)d_in[6];
  const float* gamma1 = (const float*)d_in[8];
  const float* beta1 = (const float*)d_in[9];
  const float* W_mu = (const float*)d_in[10];
  const float* b_mu = (const float*)d_in[11];
  const float* W_lv = (const float*)d_in[12];
  const float* b_lv = (const float*)d_in[13];
  float* out = (float*)d_out;

  // workspace carve: cnt|cursor|statsAll contiguous -> one memset
  bf16_t* g16 = (bf16_t*)d_ws;                        // NN*256 (slice-major)
  bf16_t* agg16 = g16 + (size_t)NN * 256;             // NN*256 (slice-major)
  int* cnt = (int*)(agg16 + (size_t)NN * 256);        // NN
  int* cursor = cnt + NN;                             // NN
  float* statsAll = (float*)(cursor + NN);            // 1024 (2 layers x 512)
  float* dinv = statsAll + 1024;                      // NN
  float* bnsc0 = dinv + NN;
  float* bnsh0 = bnsc0 + FD;
  float* bnsc1 = bnsh0 + FD;
  float* bnsh1 = bnsc1 + FD;
  float* biash = bnsh1 + FD;                          // 256
  bf16_t* W0s = (bf16_t*)(biash + 256);               // 65536 each
  bf16_t* W1s = W0s + 256 * 256;
  bf16_t* Whs = W1s + 256 * 256;
  int* row_ptr = (int*)(Whs + 256 * 256);             // NN+4
  int* col = row_ptr + NN + 4;                        // NE
  int* partials = col + NE;                           // 64

  const int SCAN_BLKS = (NN + 1023) / 1024;  // 49

  hipMemsetAsync(cnt, 0, (2 * NN + 1024) * sizeof(int), stream);
  k_count<<<(NE + 255) / 256, 256, 0, stream>>>(edst, cnt);
  k_scanA<<<SCAN_BLKS, 256, 0, stream>>>(cnt, row_ptr, partials);
  k_scanB<<<1, 64, 0, stream>>>(partials, row_ptr, SCAN_BLKS);
  k_scanC<<<SCAN_BLKS, 256, 0, stream>>>(row_ptr, partials, cnt, dinv);
  k_fill<<<(NE + 255) / 256, 256, 0, stream>>>(esrc, edst, row_ptr, cursor, col);
  k_convw<<<256, 256, 0, stream>>>(W0, W1, W_mu, b_mu, W_lv, b_lv, W0s, W1s,
                                   Whs, biash);

  dim3 gg((NN + 127) / 128, 2);
  const int SPMM_BLKS = 8 * ((NN + 63) / 64);  // 6256, slice = bid & 7

  // layer 0
  k_mgemm<<<gg, 256, 0, stream>>>(x, 1, W0s, g16, nullptr, NN, nullptr, nullptr,
                                  dinv, nullptr, 0);
  k_spmm<<<SPMM_BLKS, 256, 0, stream>>>(g16, row_ptr, col, dinv, agg16, statsAll);
  k_bnfinal<<<1, FD, 0, stream>>>(statsAll, gamma0, beta0, bnsc0, bnsh0);

  // layer 1
  k_mgemm<<<gg, 256, 0, stream>>>(agg16, 0, W1s, g16, nullptr, NN, bnsc0, bnsh0,
                                  dinv, nullptr, 0);
  k_spmm<<<SPMM_BLKS, 256, 0, stream>>>(g16, row_ptr, col, dinv, agg16,
                                        statsAll + 512);
  k_bnfinal<<<1, FD, 0, stream>>>(statsAll + 512, gamma1, beta1, bnsc1, bnsh1);

  // heads (fused mu|logvar)
  k_mgemm<<<gg, 256, 0, stream>>>(agg16, 0, Whs, nullptr, out, NN, bnsc1, bnsh1,
                                  nullptr, biash, 1);
}

// Round 3
// 470.627 us; speedup vs baseline: 1.0342x; 1.0342x over previous
//
#include <hip/hip_runtime.h>
#include <hip/hip_bf16.h>

#define NN 50000
#define NP 50001  // row stride incl. zero-row at index NN
#define NE 800000
#define FD 256
#define LD 128
#define BN_EPS 1e-5f
#define NEPAD (NE + 7 * NN + 16)

typedef __bf16 bf16_t;
typedef bf16_t bf16x8 __attribute__((ext_vector_type(8)));
typedef float f32x4 __attribute__((ext_vector_type(4)));
typedef float f32x2 __attribute__((ext_vector_type(2)));
typedef int i32x4 __attribute__((ext_vector_type(4)));
typedef unsigned int u32x4 __attribute__((ext_vector_type(4)));

// ---------------- CSR build ----------------

__global__ __launch_bounds__(256) void k_count(const int* __restrict__ dst,
                                               int* __restrict__ cnt) {
  int i = blockIdx.x * blockDim.x + threadIdx.x;
  if (i < NE) atomicAdd(&cnt[dst[i]], 1);
}

// scans PADDED counts (each row padded to multiple of 8 edges)
__global__ __launch_bounds__(256) void k_scanA(const int* __restrict__ cnt,
                                               int* __restrict__ row_ptr,
                                               int* __restrict__ partials) {
  __shared__ int ws[4];
  int b = blockIdx.x, t = threadIdx.x;
  int base = b * 1024 + t * 4;
  int vals[4];
#pragma unroll
  for (int j = 0; j < 4; ++j)
    vals[j] = (base + j < NN) ? ((cnt[base + j] + 7) & ~7) : 0;
  int tsum = vals[0] + vals[1] + vals[2] + vals[3];
  int lane = t & 63, wid = t >> 6;
  int x = tsum;
#pragma unroll
  for (int off = 1; off < 64; off <<= 1) {
    int y = __shfl_up(x, off, 64);
    if (lane >= off) x += y;
  }
  if (lane == 63) ws[wid] = x;
  __syncthreads();
  int woff = 0;
  for (int w = 0; w < wid; ++w) woff += ws[w];
  int run = woff + x - tsum;
#pragma unroll
  for (int j = 0; j < 4; ++j) {
    if (base + j < NN) row_ptr[base + j] = run;
    run += vals[j];
  }
  if (t == 255) partials[b] = woff + x;
}

__global__ void k_scanB(int* __restrict__ partials, int* __restrict__ row_ptr,
                        int nblk) {
  int lane = threadIdx.x;
  int v = (lane < nblk) ? partials[lane] : 0;
  int x = v;
#pragma unroll
  for (int off = 1; off < 64; off <<= 1) {
    int y = __shfl_up(x, off, 64);
    if (lane >= off) x += y;
  }
  if (lane < nblk) partials[lane] = x - v;
  if (lane == nblk - 1) row_ptr[NN] = x;  // total padded edges
}

// scanC: finalize row_ptr, dinv, and fill padding slots with zero-row index
__global__ __launch_bounds__(256) void k_scanC(int* __restrict__ row_ptr,
                                               const int* __restrict__ partials,
                                               const int* __restrict__ cnt,
                                               float* __restrict__ dinv,
                                               int* __restrict__ col) {
  int b = blockIdx.x;
  int off = partials[b];
  int base = b * 1024 + threadIdx.x * 4;
#pragma unroll
  for (int j = 0; j < 4; ++j)
    if (base + j < NN) {
      int deg = cnt[base + j];
      int rp = row_ptr[base + j] + off;
      row_ptr[base + j] = rp;
      dinv[base + j] = rsqrtf(1.0f + (float)deg);
      int pd = (deg + 7) & ~7;
      for (int p = deg; p < pd; ++p) col[rp + p] = NN;  // zero-row
    }
}

__global__ __launch_bounds__(256) void k_fill(const int* __restrict__ src,
                                              const int* __restrict__ dst,
                                              const int* __restrict__ row_ptr,
                                              int* __restrict__ cursor,
                                              int* __restrict__ col) {
  int i = blockIdx.x * blockDim.x + threadIdx.x;
  if (i < NE) {
    int d = dst[i];
    int p = atomicAdd(&cursor[d], 1);
    col[row_ptr[d] + p] = src[i];
  }
}

// ---------------- weight convert to MFMA-fragment-swizzled bf16 ------------
// also zeroes the padding row (index NN) of g16 / agg16 in every slice
__global__ __launch_bounds__(256) void k_convw(
    const float* __restrict__ W0, const float* __restrict__ W1,
    const float* __restrict__ Wmu, const float* __restrict__ bmu,
    const float* __restrict__ Wlv, const float* __restrict__ blv,
    bf16_t* __restrict__ W0s, bf16_t* __restrict__ W1s,
    bf16_t* __restrict__ Whs, float* __restrict__ biash,
    bf16_t* __restrict__ g16, bf16_t* __restrict__ agg16) {
  int k = blockIdx.x, n = threadIdx.x;
  int chunk = (n >> 4) * 8 + (k >> 5);
  int slot = ((k >> 3) & 3) * 16 + (n & 15);
  int idx = chunk * 512 + slot * 8 + (k & 7);
  W0s[idx] = (bf16_t)W0[k * 256 + n];
  W1s[idx] = (bf16_t)W1[k * 256 + n];
  float wh = (n < 128) ? Wmu[k * 128 + n] : Wlv[k * 128 + (n - 128)];
  Whs[idx] = (bf16_t)wh;
  if (k == 0) biash[n] = (n < 128) ? bmu[n] : blv[n - 128];
  if (k == 1) {
    int ss = n >> 5, j = n & 31;
    g16[((size_t)ss * NP + NN) * 32 + j] = (bf16_t)0.f;
    agg16[((size_t)ss * NP + NN) * 32 + j] = (bf16_t)0.f;
  }
}

// ---------------- barrier-free MFMA GEMM, batched raw loads ----------------
// bf16 activations (a_f32==0) are in SLICE-MAJOR layout [8][NP][32]:
// feature f of node r lives at (f>>5)*NP*32 + r*32 + (f&31). slice == kb.
__global__ __launch_bounds__(256) void k_mgemm(
    const void* __restrict__ Ap, int a_f32, const bf16_t* __restrict__ Wswz,
    bf16_t* __restrict__ Cb, float* __restrict__ Cf, int M,
    const float* __restrict__ bn_scale, const float* __restrict__ bn_shift,
    const float* __restrict__ row_scale, const float* __restrict__ col_bias,
    int split) {
  __shared__ bf16_t Ws[64 * 512];  // 64 chunks x 1 KB
  const int tid = threadIdx.x;
  const int half = blockIdx.y;
  {
    const bf16_t* srcW = Wswz + (size_t)half * 64 * 512;
    bf16x8 wraw[16];
#pragma unroll
    for (int i = 0; i < 16; ++i)
      wraw[i] = *(const bf16x8*)&srcW[(i * 256 + tid) * 8];
#pragma unroll
    for (int i = 0; i < 16; ++i) *(bf16x8*)&Ws[(i * 256 + tid) * 8] = wraw[i];
  }
  __syncthreads();

  const int wave = tid >> 6, lane = tid & 63;
  const int m = lane & 15, q = lane >> 4;  // A-frag: row m, k-octet q
  const int row0 = blockIdx.x * 128 + wave * 32;
  const int rg0 = row0 + m, rg1 = row0 + 16 + m;
  const int rc0 = rg0 < M ? rg0 : M - 1;
  const int rc1 = rg1 < M ? rg1 : M - 1;

  bf16x8 af[2][8];
  if (a_f32) {
    const float* p0 = (const float*)Ap + (size_t)rc0 * 256 + q * 8;
    const float* p1 = (const float*)Ap + (size_t)rc1 * 256 + q * 8;
#pragma unroll
    for (int g = 0; g < 2; ++g) {
      const float* p = g ? p1 : p0;
      float4 f0[8], f1[8];
#pragma unroll
      for (int kb = 0; kb < 8; ++kb) {
        f0[kb] = *(const float4*)(p + kb * 32);
        f1[kb] = *(const float4*)(p + kb * 32 + 4);
      }
#pragma unroll
      for (int kb = 0; kb < 8; ++kb) {
        bf16x8 fr;
        fr[0] = (bf16_t)f0[kb].x; fr[1] = (bf16_t)f0[kb].y;
        fr[2] = (bf16_t)f0[kb].z; fr[3] = (bf16_t)f0[kb].w;
        fr[4] = (bf16_t)f1[kb].x; fr[5] = (bf16_t)f1[kb].y;
        fr[6] = (bf16_t)f1[kb].z; fr[7] = (bf16_t)f1[kb].w;
        af[g][kb] = fr;
      }
    }
  } else {
    const bf16_t* pA = (const bf16_t*)Ap;
    bf16x8 raw[16];
#pragma unroll
    for (int kb = 0; kb < 8; ++kb) {
      raw[kb * 2 + 0] =
          *(const bf16x8*)&pA[((size_t)kb * NP + rc0) * 32 + q * 8];
      raw[kb * 2 + 1] =
          *(const bf16x8*)&pA[((size_t)kb * NP + rc1) * 32 + q * 8];
    }
#pragma unroll
    for (int kb = 0; kb < 8; ++kb) {
      float s[8], h[8];
      if (bn_scale) {
        float4 s0 = *(const float4*)&bn_scale[kb * 32 + q * 8];
        float4 s1 = *(const float4*)&bn_scale[kb * 32 + q * 8 + 4];
        float4 h0 = *(const float4*)&bn_shift[kb * 32 + q * 8];
        float4 h1 = *(const float4*)&bn_shift[kb * 32 + q * 8 + 4];
        s[0] = s0.x; s[1] = s0.y; s[2] = s0.z; s[3] = s0.w;
        s[4] = s1.x; s[5] = s1.y; s[6] = s1.z; s[7] = s1.w;
        h[0] = h0.x; h[1] = h0.y; h[2] = h0.z; h[3] = h0.w;
        h[4] = h1.x; h[5] = h1.y; h[6] = h1.z; h[7] = h1.w;
      }
#pragma unroll
      for (int g = 0; g < 2; ++g) {
        bf16x8 r = raw[kb * 2 + g];
        bf16x8 fr;
#pragma unroll
        for (int j = 0; j < 8; ++j) {
          float v = (float)r[j];
          if (bn_scale) v = fmaxf(fmaf(v, s[j], h[j]), 0.f);
          fr[j] = (bf16_t)v;
        }
        af[g][kb] = fr;
      }
    }
  }

  f32x4 acc[2][8] = {};
#pragma unroll
  for (int nt = 0; nt < 8; ++nt) {
#pragma unroll
    for (int kb = 0; kb < 8; ++kb) {
      bf16x8 b = *(const bf16x8*)&Ws[(nt * 8 + kb) * 512 + lane * 8];
      acc[0][nt] = __builtin_amdgcn_mfma_f32_16x16x32_bf16(af[0][kb], b,
                                                           acc[0][nt], 0, 0, 0);
      acc[1][nt] = __builtin_amdgcn_mfma_f32_16x16x32_bf16(af[1][kb], b,
                                                           acc[1][nt], 0, 0, 0);
    }
  }

  // epilogue: D row_local = q*4 + r, col_local = m  [m89-verified layout]
#pragma unroll
  for (int g = 0; g < 2; ++g) {
#pragma unroll
    for (int r = 0; r < 4; ++r) {
      int row = row0 + g * 16 + q * 4 + r;
      if (row >= M) continue;
      float rs = row_scale ? row_scale[row] : 1.0f;
#pragma unroll
      for (int nt = 0; nt < 8; ++nt) {
        int col = half * 128 + nt * 16 + m;
        float v = acc[g][nt][r] * rs;
        if (col_bias) v += col_bias[col];
        if (Cb) {
          Cb[((size_t)(col >> 5) * NP + row) * 32 + (col & 31)] = (bf16_t)v;
        } else if (!split) {
          Cf[(size_t)row * 256 + col] = v;
        } else {
          if (col < 128)
            Cf[(size_t)row * 128 + col] = v;
          else
            Cf[(size_t)(M + row) * 128 + (col - 128)] = v;
        }
      }
    }
  }
}

// ---------------- SpMM + fused BN stats, XCD-pinned feature slices --------
// g / out slice-major [8][NP][32]. slice = blockIdx.x & 7 (round-robin pins
// slice s to XCD s; 3.2 MB slice L2-resident). Teams of 4 lanes, 1 dst row.
// Rows padded to x8 edges (padding -> zero-row NN): per iteration each lane
// loads ALL 8 neighbor ids itself (2 aligned 16B vec loads) -- no shuffles,
// no lgkm in the chain; next col block is prefetched while the 8 gathers
// are in flight.
__global__ __launch_bounds__(256) void k_spmm(const bf16_t* __restrict__ g,
                                              const int* __restrict__ row_ptr,
                                              const int* __restrict__ col,
                                              const float* __restrict__ dinv,
                                              bf16_t* __restrict__ out,
                                              float* __restrict__ stats) {
  __shared__ float sbuf[64][32];
  const int s = blockIdx.x & 7;
  const int grp = blockIdx.x >> 3;
  const int team = threadIdx.x >> 2, tl = threadIdx.x & 3;
  const int dst = grp * 64 + team;
  const u32x4* gu = (const u32x4*)(g + (size_t)s * NP * 32);  // node*4 + tl
  f32x2 acc[4] = {{0.f, 0.f}, {0.f, 0.f}, {0.f, 0.f}, {0.f, 0.f}};
  float s1[8] = {}, s2[8] = {};
  if (dst < NN) {
    int b0 = row_ptr[dst], e = row_ptr[dst + 1];
    {
      u32x4 d = gu[(size_t)dst * 4 + tl];
      acc[0] += (f32x2){__uint_as_float(d[0] << 16),
                        __uint_as_float(d[0] & 0xffff0000u)};
      acc[1] += (f32x2){__uint_as_float(d[1] << 16),
                        __uint_as_float(d[1] & 0xffff0000u)};
      acc[2] += (f32x2){__uint_as_float(d[2] << 16),
                        __uint_as_float(d[2] & 0xffff0000u)};
      acc[3] += (f32x2){__uint_as_float(d[3] << 16),
                        __uint_as_float(d[3] & 0xffff0000u)};
    }
    i32x4 c0 = {}, c1 = {};
    if (b0 < e) {
      c0 = __builtin_nontemporal_load((const i32x4*)&col[b0]);
      c1 = __builtin_nontemporal_load((const i32x4*)&col[b0 + 4]);
    }
    while (b0 < e) {
      int bn = b0 + 8;
      // issue 8 gathers for current batch
      u32x4 w0 = gu[(size_t)c0[0] * 4 + tl];
      u32x4 w1 = gu[(size_t)c0[1] * 4 + tl];
      u32x4 w2 = gu[(size_t)c0[2] * 4 + tl];
      u32x4 w3 = gu[(size_t)c0[3] * 4 + tl];
      u32x4 w4 = gu[(size_t)c1[0] * 4 + tl];
      u32x4 w5 = gu[(size_t)c1[1] * 4 + tl];
      u32x4 w6 = gu[(size_t)c1[2] * 4 + tl];
      u32x4 w7 = gu[(size_t)c1[3] * 4 + tl];
      // prefetch next col block while gathers are in flight
      i32x4 n0 = {}, n1 = {};
      if (bn < e) {
        n0 = __builtin_nontemporal_load((const i32x4*)&col[bn]);
        n1 = __builtin_nontemporal_load((const i32x4*)&col[bn + 4]);
      }
#define ACCUM(d)                                                     \
  acc[0] += (f32x2){__uint_as_float(d[0] << 16),                     \
                    __uint_as_float(d[0] & 0xffff0000u)};            \
  acc[1] += (f32x2){__uint_as_float(d[1] << 16),                     \
                    __uint_as_float(d[1] & 0xffff0000u)};            \
  acc[2] += (f32x2){__uint_as_float(d[2] << 16),                     \
                    __uint_as_float(d[2] & 0xffff0000u)};            \
  acc[3] += (f32x2){__uint_as_float(d[3] << 16),                     \
                    __uint_as_float(d[3] & 0xffff0000u)};
      ACCUM(w0) ACCUM(w1) ACCUM(w2) ACCUM(w3)
      ACCUM(w4) ACCUM(w5) ACCUM(w6) ACCUM(w7)
#undef ACCUM
      c0 = n0;
      c1 = n1;
      b0 = bn;
    }
    float dv = dinv[dst];
    bf16x8 ov;
#pragma unroll
    for (int j = 0; j < 8; ++j) ov[j] = (bf16_t)(acc[j >> 1][j & 1] * dv);
    __builtin_nontemporal_store(
        ov, (bf16x8*)&out[((size_t)s * NP + dst) * 32 + (size_t)tl * 8]);
#pragma unroll
    for (int j = 0; j < 8; ++j) {
      float vq = (float)ov[j];
      s1[j] += vq;
      s2[j] = fmaf(vq, vq, s2[j]);
    }
  }
  // block reduction of stats (32 feats of this slice across 64 teams)
#pragma unroll
  for (int j = 0; j < 8; ++j) sbuf[team][tl * 8 + j] = s1[j];
  __syncthreads();
  if (threadIdx.x < 32) {
    float tot = 0.f;
#pragma unroll
    for (int w = 0; w < 64; ++w) tot += sbuf[w][threadIdx.x];
    atomicAdd(&stats[s * 32 + threadIdx.x], tot);
  }
  __syncthreads();
#pragma unroll
  for (int j = 0; j < 8; ++j) sbuf[team][tl * 8 + j] = s2[j];
  __syncthreads();
  if (threadIdx.x < 32) {
    float tot = 0.f;
#pragma unroll
    for (int w = 0; w < 64; ++w) tot += sbuf[w][threadIdx.x];
    atomicAdd(&stats[256 + s * 32 + threadIdx.x], tot);
  }
}

__global__ __launch_bounds__(256) void k_bnfinal(const float* __restrict__ stats,
                                                 const float* __restrict__ gamma,
                                                 const float* __restrict__ beta,
                                                 float* __restrict__ bnsc,
                                                 float* __restrict__ bnsh) {
  int t = threadIdx.x;
  float mean = stats[t] * (1.0f / NN);
  float var = stats[256 + t] * (1.0f / NN) - mean * mean;
  float rs = rsqrtf(var + BN_EPS);
  float sc = gamma[t] * rs;
  bnsc[t] = sc;
  bnsh[t] = beta[t] - mean * sc;
}

// ---------------- launch ----------------
extern "C" void kernel_launch(void* const* d_in, const int* in_sizes, int n_in,
                              void* d_out, int out_size, void* d_ws, size_t ws_size,
                              hipStream_t stream) {
  const float* x = (const float*)d_in[0];
  const int* ei = (const int*)d_in[1];
  const int* esrc = ei;
  const int* edst = ei + NE;
  const float* W0 = (const float*)d_in[2];
  const float* gamma0 = (const float*)d_in[4];
  const float* beta0 = (const float*)d_in[5];
  const float* W1 = (const float*)d_in[6];
  const float* gamma1 = (const float*)d_in[8];
  const float* beta1 = (const float*)d_in[9];
  const float* W_mu = (const float*)d_in[10];
  const float* b_mu = (const float*)d_in[11];
  const float* W_lv = (const float*)d_in[12];
  const float* b_lv = (const float*)d_in[13];
  float* out = (float*)d_out;

  // workspace carve: cnt|cursor|statsAll contiguous -> one memset
  bf16_t* g16 = (bf16_t*)d_ws;                        // 8*NP*32 (slice-major)
  bf16_t* agg16 = g16 + (size_t)8 * NP * 32;          // 8*NP*32 (slice-major)
  int* cnt = (int*)(agg16 + (size_t)8 * NP * 32);     // NN
  int* cursor = cnt + NN;                             // NN
  float* statsAll = (float*)(cursor + NN);            // 1024 (2 layers x 512)
  float* dinv = statsAll + 1024;                      // NN
  float* bnsc0 = dinv + NN;
  float* bnsh0 = bnsc0 + FD;
  float* bnsc1 = bnsh0 + FD;
  float* bnsh1 = bnsc1 + FD;
  float* biash = bnsh1 + FD;                          // 256
  bf16_t* W0s = (bf16_t*)(biash + 256);               // 65536 each
  bf16_t* W1s = W0s + 256 * 256;
  bf16_t* Whs = W1s + 256 * 256;
  int* row_ptr = (int*)(Whs + 256 * 256);             // NN+4 (keeps 16B align)
  int* col = row_ptr + NN + 4;                        // NEPAD (16B aligned)
  int* partials = col + NEPAD;                        // 64

  const int SCAN_BLKS = (NN + 1023) / 1024;  // 49

  hipMemsetAsync(cnt, 0, (2 * NN + 1024) * sizeof(int), stream);
  k_count<<<(NE + 255) / 256, 256, 0, stream>>>(edst, cnt);
  k_scanA<<<SCAN_BLKS, 256, 0, stream>>>(cnt, row_ptr, partials);
  k_scanB<<<1, 64, 0, stream>>>(partials, row_ptr, SCAN_BLKS);
  k_scanC<<<SCAN_BLKS, 256, 0, stream>>>(row_ptr, partials, cnt, dinv, col);
  k_fill<<<(NE + 255) / 256, 256, 0, stream>>>(esrc, edst, row_ptr, cursor, col);
  k_convw<<<256, 256, 0, stream>>>(W0, W1, W_mu, b_mu, W_lv, b_lv, W0s, W1s,
                                   Whs, biash, g16, agg16);

  dim3 gg((NN + 127) / 128, 2);
  const int SPMM_BLKS = 8 * ((NN + 63) / 64);  // 6256, slice = bid & 7

  // layer 0
  k_mgemm<<<gg, 256, 0, stream>>>(x, 1, W0s, g16, nullptr, NN, nullptr, nullptr,
                                  dinv, nullptr, 0);
  k_spmm<<<SPMM_BLKS, 256, 0, stream>>>(g16, row_ptr, col, dinv, agg16, statsAll);
  k_bnfinal<<<1, FD, 0, stream>>>(statsAll, gamma0, beta0, bnsc0, bnsh0);

  // layer 1
  k_mgemm<<<gg, 256, 0, stream>>>(agg16, 0, W1s, g16, nullptr, NN, bnsc0, bnsh0,
                                  dinv, nullptr, 0);
  k_spmm<<<SPMM_BLKS, 256, 0, stream>>>(g16, row_ptr, col, dinv, agg16,
                                        statsAll + 512);
  k_bnfinal<<<1, FD, 0, stream>>>(statsAll + 512, gamma1, beta1, bnsc1, bnsh1);

  // heads (fused mu|logvar)
  k_mgemm<<<gg, 256, 0, stream>>>(agg16, 0, Whs, nullptr, out, NN, bnsc1, bnsh1,
                                  nullptr, biash, 1);
}